// Round 3
// baseline (77.045 us; speedup 1.0000x reference)
//
#include <hip/hip_runtime.h>

// LocallyConnected3D: out[b, od,oh,ow, f] = sum_p patch[b,l,p] * W[l,p,f] + bias[l,f]
// B=4, x=(4,32,32,32,8) f32, W=(27000,216,16) f32 (373 MB, streamed once),
// bias=(30,30,30,16), out=(4,30,30,30,16).
// HBM-bound on the weight stream -> one wave per output location, weights
// loaded as 27 fully-coalesced float2 loads (512 B/wave/instr) into registers.

#define ODIM 30
#define LLOC 27000
#define PDIM 216
#define FDIM 16
#define CIN 8

__global__ __launch_bounds__(64) void lc3d_kernel(
    const float* __restrict__ x,
    const float* __restrict__ w,
    const float* __restrict__ bias,
    float* __restrict__ out)
{
    const int l = blockIdx.x;           // output location
    const int lane = threadIdx.x;       // 0..63
    const int od = l / 900;
    const int rl = l - od * 900;
    const int oh = rl / 30;
    const int ow = rl - oh * 30;

    __shared__ float patch[4 * PDIM];   // [b][p], p = kd*72 + kh*24 + kw*8 + c

    // ---- Phase 1: gather receptive field into LDS (216 float4 chunks) ----
    #pragma unroll
    for (int i = 0; i < 4; ++i) {
        int idx = i * 64 + lane;
        if (idx < 216) {
            int b    = idx / 54;            // 54 float4 per batch
            int r    = idx - b * 54;
            int slab = r >> 1;              // kd*9 + kh*3 + kw
            int half = r & 1;
            int kd   = slab / 9;
            int r2   = slab - kd * 9;
            int kh   = r2 / 3;
            int kw   = r2 - kh * 3;
            const float4 v = *reinterpret_cast<const float4*>(
                x + ((((b * 32 + od + kd) * 32 + (oh + kh)) * 32 + (ow + kw)) * CIN
                     + half * 4));
            *reinterpret_cast<float4*>(&patch[b * PDIM + slab * 8 + half * 4]) = v;
        }
    }
    __syncthreads();

    // ---- Phase 2: stream weights, accumulate ----
    // lane = pidx*8 + fh : pidx in [0,8) covers p % 8, fh in [0,8) covers f pair
    const int pidx = lane >> 3;
    const int fh   = lane & 7;

    const float2* wbase =
        reinterpret_cast<const float2*>(w + (size_t)l * (PDIM * FDIM));

    float2 wr[27];
    #pragma unroll
    for (int i = 0; i < 27; ++i)
        wr[i] = wbase[i * 64 + lane];   // contiguous 512 B per wave per i

    float acc[4][2] = {};
    #pragma unroll
    for (int i = 0; i < 27; ++i) {
        const int p = i * 8 + pidx;
        #pragma unroll
        for (int b = 0; b < 4; ++b) {
            const float pv = patch[b * PDIM + p];   // LDS broadcast (8 lanes/addr)
            acc[b][0] = fmaf(pv, wr[i].x, acc[b][0]);
            acc[b][1] = fmaf(pv, wr[i].y, acc[b][1]);
        }
    }

    // ---- Phase 3: reduce partial sums across the 8 pidx groups ----
    #pragma unroll
    for (int b = 0; b < 4; ++b) {
        #pragma unroll
        for (int j = 0; j < 2; ++j) {
            float v = acc[b][j];
            v += __shfl_xor(v, 8, 64);
            v += __shfl_xor(v, 16, 64);
            v += __shfl_xor(v, 32, 64);
            acc[b][j] = v;
        }
    }

    // ---- Epilogue: lanes 0..7 (pidx==0) hold full sums; write all 4 batches ----
    if (pidx == 0) {
        const float2 bv =
            *reinterpret_cast<const float2*>(bias + l * FDIM + fh * 2);
        #pragma unroll
        for (int b = 0; b < 4; ++b) {
            float2 o;
            o.x = acc[b][0] + bv.x;
            o.y = acc[b][1] + bv.y;
            *reinterpret_cast<float2*>(
                out + ((size_t)b * LLOC + l) * FDIM + fh * 2) = o;
        }
    }
}

extern "C" void kernel_launch(void* const* d_in, const int* in_sizes, int n_in,
                              void* d_out, int out_size, void* d_ws, size_t ws_size,
                              hipStream_t stream) {
    const float* x    = (const float*)d_in[0];
    const float* wgt  = (const float*)d_in[1];
    const float* bias = (const float*)d_in[2];
    float* out        = (float*)d_out;

    lc3d_kernel<<<dim3(LLOC), dim3(64), 0, stream>>>(x, wgt, bias, out);
}

// Round 6
// 74.198 us; speedup vs baseline: 1.0384x; 1.0384x over previous
//
#include <hip/hip_runtime.h>

// LocallyConnected3D: out[b,l,f] = sum_p patch[b,l,p] * W[l,p,f] + bias[l,f]
// W = (27000,216,16) f32 = 373 MB streamed once -> HBM-bound, floor ~61us.
// One wave per location. Barrier-free: block=64 is exactly one wave, and the
// wave only touches its own LDS, so program-order lgkmcnt suffices — no
// __syncthreads (which would force a vmcnt(0) drain of the weight stream).
// Load order: x (older, 4 float4) -> weights (27 x 512B coalesced float2) ->
// ds_write patch (waits vmcnt(27): weight stream stays in flight) ->
// FMA with progressive counted vmcnt per wr[i].

#define LLOC 27000
#define PDIM 216
#define FDIM 16
#define CIN 8

__global__ __launch_bounds__(64) void lc3d_kernel(
    const float* __restrict__ x,
    const float* __restrict__ w,
    const float* __restrict__ bias,
    float* __restrict__ out)
{
    const int l = blockIdx.x;
    const int lane = threadIdx.x;       // 0..63
    const int od = l / 900;
    const int rl = l - od * 900;
    const int oh = rl / 30;
    const int ow = rl - oh * 30;

    __shared__ float patch[4 * PDIM];   // [b][p], p = (kd*9+kh*3+kw)*8 + c

    // ---- Phase 1a: issue x gather loads into registers (no divergence:
    //      invalid lanes load a clamped address and just don't write LDS) ----
    float4 xv[4];
    int ldst[4];
    #pragma unroll
    for (int i = 0; i < 4; ++i) {
        const int idx   = i * 64 + lane;        // 0..255, 216 real chunks
        const bool vld  = idx < 216;
        const int cidx  = vld ? idx : 0;
        const int b     = cidx / 54;            // 54 float4 per batch
        const int r     = cidx - b * 54;
        const int slab  = r >> 1;               // kd*9 + kh*3 + kw
        const int half  = r & 1;
        const int kd    = slab / 9;
        const int r2    = slab - kd * 9;
        const int kh    = r2 / 3;
        const int kw    = r2 - kh * 3;
        ldst[i] = vld ? (b * PDIM + slab * 8 + half * 4) : -1;
        xv[i] = *reinterpret_cast<const float4*>(
            x + ((((b * 32 + od + kd) * 32 + (oh + kh)) * 32 + (ow + kw)) * CIN
                 + half * 4));
    }

    // ---- Phase 1b: issue the BW-critical weight stream (27 x 512B/wave) ----
    const int pidx = lane >> 3;                 // p % 8   (== input channel c)
    const int fh   = lane & 7;                  // f pair index
    const float2* wbase =
        reinterpret_cast<const float2*>(w + (size_t)l * (PDIM * FDIM));
    float2 wr[27];
    #pragma unroll
    for (int i = 0; i < 27; ++i)
        wr[i] = wbase[i * 64 + lane];

    // ---- Phase 1c: write patch to LDS (waits only on x loads; weight
    //      loads remain outstanding in the vmcnt FIFO) ----
    #pragma unroll
    for (int i = 0; i < 4; ++i)
        if (ldst[i] >= 0)
            *reinterpret_cast<float4*>(&patch[ldst[i]]) = xv[i];

    // ---- Phase 2: FMA; compiler emits progressive vmcnt per wr[i] ----
    float acc[4][2] = {};
    #pragma unroll
    for (int i = 0; i < 27; ++i) {
        const int p = i * 8 + pidx;
        #pragma unroll
        for (int b = 0; b < 4; ++b) {
            const float pv = patch[b * PDIM + p];   // LDS broadcast, conflict-free
            acc[b][0] = fmaf(pv, wr[i].x, acc[b][0]);
            acc[b][1] = fmaf(pv, wr[i].y, acc[b][1]);
        }
    }

    // ---- Phase 3: reduce across the 8 pidx groups ----
    #pragma unroll
    for (int b = 0; b < 4; ++b) {
        #pragma unroll
        for (int j = 0; j < 2; ++j) {
            float v = acc[b][j];
            v += __shfl_xor(v, 8, 64);
            v += __shfl_xor(v, 16, 64);
            v += __shfl_xor(v, 32, 64);
            acc[b][j] = v;
        }
    }

    // ---- Epilogue: lanes 0..7 hold full sums; write all 4 batches ----
    if (pidx == 0) {
        const float2 bv =
            *reinterpret_cast<const float2*>(bias + l * FDIM + fh * 2);
        #pragma unroll
        for (int b = 0; b < 4; ++b) {
            float2 o;
            o.x = acc[b][0] + bv.x;
            o.y = acc[b][1] + bv.y;
            *reinterpret_cast<float2*>(
                out + ((size_t)b * LLOC + l) * FDIM + fh * 2) = o;
        }
    }
}

extern "C" void kernel_launch(void* const* d_in, const int* in_sizes, int n_in,
                              void* d_out, int out_size, void* d_ws, size_t ws_size,
                              hipStream_t stream) {
    const float* x    = (const float*)d_in[0];
    const float* wgt  = (const float*)d_in[1];
    const float* bias = (const float*)d_in[2];
    float* out        = (float*)d_out;

    lc3d_kernel<<<dim3(LLOC), dim3(64), 0, stream>>>(x, wgt, bias, out);
}